// Round 1
// baseline (519.748 us; speedup 1.0000x reference)
//
#include <hip/hip_runtime.h>

#define HW    256
#define HW2   65536      // HW*HW
#define BS    128
#define QPB   16384      // float4 quads per image plane (HW2/4)

// ---------------------------------------------------------------------------
// Kernel A: per-batch count of seg>0.5 ; flags[b] = (count==0)
// ---------------------------------------------------------------------------
__global__ void count_kernel(const float* __restrict__ seg, int* __restrict__ flags) {
    int b = blockIdx.x;
    const float4* s4 = (const float4*)(seg + (size_t)b * HW2);
    int cnt = 0;
    for (int i = threadIdx.x; i < QPB; i += blockDim.x) {
        float4 v = s4[i];
        cnt += (v.x > 0.5f) + (v.y > 0.5f) + (v.z > 0.5f) + (v.w > 0.5f);
    }
    __shared__ int red[4];
    for (int off = 32; off > 0; off >>= 1) cnt += __shfl_down(cnt, off);
    int wave = threadIdx.x >> 6;
    int lane = threadIdx.x & 63;
    if (lane == 0) red[wave] = cnt;
    __syncthreads();
    if (threadIdx.x == 0) {
        int t = red[0] + red[1] + red[2] + red[3];
        flags[b] = (t == 0) ? 1 : 0;
    }
}

// ---------------------------------------------------------------------------
// Kernel B: scatter. W[b, gy, gx] = max over writers of (h*256+w).
// Masked pixels (seg<=0.5, no fallback) all target cell (128,128):
// wave-reduce those to a single atomic (highest active lane carries wave max).
// ---------------------------------------------------------------------------
__global__ void scatter_kernel(const float* __restrict__ grid,
                               const float* __restrict__ seg,
                               const int* __restrict__ flags,
                               int* __restrict__ W) {
    int idx4 = blockIdx.x * blockDim.x + threadIdx.x;   // one float4 (4 pixels)
    int b   = idx4 >> 14;          // QPB = 2^14
    int rem = idx4 & (QPB - 1);
    int flagb = flags ? flags[b] : 0;

    const float4 gx = ((const float4*)(grid + (size_t)(2 * b) * HW2))[rem];
    const float4 gy = ((const float4*)(grid + (size_t)(2 * b + 1) * HW2))[rem];
    const float4 sv = ((const float4*)(seg + (size_t)b * HW2))[rem];

    int* Wb = W + (size_t)b * HW2;
    int hw0 = rem * 4;

    float sarr[4] = {sv.x, sv.y, sv.z, sv.w};
    float xarr[4] = {gx.x, gx.y, gx.z, gx.w};
    float yarr[4] = {gy.x, gy.y, gy.z, gy.w};

    int masked_max = -1;
#pragma unroll
    for (int j = 0; j < 4; ++j) {
        bool m = flagb || (sarr[j] > 0.5f);
        if (m) {
            // ((g+1)*0.5)*256 ; trunc toward zero (g+1 >= 0 so == floor) ; clamp
            float fx = (xarr[j] + 1.0f) * 0.5f * 256.0f;
            float fy = (yarr[j] + 1.0f) * 0.5f * 256.0f;
            int gxi = min(max((int)fx, 0), HW - 1);
            int gyi = min(max((int)fy, 0), HW - 1);
            atomicMax(&Wb[gyi * HW + gxi], hw0 + j);
        } else {
            masked_max = hw0 + j;   // gridm == 0 -> cell (128,128)
        }
    }
    unsigned long long bal = __ballot(masked_max >= 0);
    if (masked_max >= 0) {
        int hi = 63 - __clzll(bal);
        if ((threadIdx.x & 63) == hi)
            atomicMax(&Wb[128 * HW + 128], masked_max);
    }
}

// ---------------------------------------------------------------------------
// Kernel C: gather + write all outputs.
// l = W[b,h,w]; l<0 -> (ix,iy)=(0,0) else ix=(l&255)&~1, iy=(l>>8)&~1
//   (round-half-even of uv-0.5 for integer uv picks the even neighbor).
// dkpt_uv = [ix/280, iy/280, depth[iy,ix]] * mask ; conf_uv = conf[iy,ix];
// mask_uv = mask.   (validity multiplier is always 1 here.)
// NOTE: no __restrict__ on W/out — W may alias the mask_uv region when ws is
// too small; per-cell the load precedes the (data-dependent) store.
// ---------------------------------------------------------------------------
__global__ void gather_kernel(const int* W,
                              const float* __restrict__ seg,
                              const float* __restrict__ conf,
                              const float* __restrict__ depth,
                              const int* __restrict__ flags,
                              float* out) {
    int idx4 = blockIdx.x * blockDim.x + threadIdx.x;
    int b   = idx4 >> 14;
    int rem = idx4 & (QPB - 1);
    int flagb = flags ? flags[b] : 0;

    int4 wv = ((const int4*)(W + (size_t)b * HW2))[rem];
    const float* segb   = seg   + (size_t)b * HW2;
    const float* confb  = conf  + (size_t)b * HW2;
    const float* depthb = depth + (size_t)b * HW2;

    int larr[4] = {wv.x, wv.y, wv.z, wv.w};
    float o0[4], o1[4], o2[4], oc[4], om[4];
#pragma unroll
    for (int j = 0; j < 4; ++j) {
        int l = larr[j];
        int ix, iy;
        if (l < 0) { ix = 0; iy = 0; }
        else       { ix = (l & 255) & ~1; iy = (l >> 8) & ~1; }
        int off = iy * HW + ix;
        float m = flagb ? 1.0f : (segb[off] > 0.5f ? 1.0f : 0.0f);
        o0[j] = ((float)ix / 280.0f) * m;
        o1[j] = ((float)iy / 280.0f) * m;
        o2[j] = depthb[off] * m;
        oc[j] = confb[off];
        om[j] = m;
    }

    float4* out4 = (float4*)out;
    size_t dk = (size_t)(b * 3) * QPB + rem;
    out4[dk]            = make_float4(o0[0], o0[1], o0[2], o0[3]);
    out4[dk + QPB]      = make_float4(o1[0], o1[1], o1[2], o1[3]);
    out4[dk + 2 * QPB]  = make_float4(o2[0], o2[1], o2[2], o2[3]);
    const size_t O1q = (size_t)BS * 3 * QPB;
    const size_t O2q = O1q + (size_t)BS * QPB;
    out4[O1q + (size_t)b * QPB + rem] = make_float4(oc[0], oc[1], oc[2], oc[3]);
    out4[O2q + (size_t)b * QPB + rem] = make_float4(om[0], om[1], om[2], om[3]);
}

// ---------------------------------------------------------------------------
extern "C" void kernel_launch(void* const* d_in, const int* in_sizes, int n_in,
                              void* d_out, int out_size, void* d_ws, size_t ws_size,
                              hipStream_t stream) {
    const float* grid  = (const float*)d_in[0];
    const float* seg   = (const float*)d_in[1];
    const float* conf  = (const float*)d_in[2];
    const float* depth = (const float*)d_in[3];
    float* out = (float*)d_out;

    const size_t Wbytes = (size_t)BS * HW2 * sizeof(int);
    int* flags = nullptr;
    int* W;
    if (ws_size >= 512 + Wbytes) {
        flags = (int*)d_ws;
        W = (int*)((char*)d_ws + 512);
    } else if (ws_size >= 512) {
        flags = (int*)d_ws;
        W = (int*)(out + (size_t)BS * 4 * HW2);   // alias mask_uv region
    } else {
        W = (int*)(out + (size_t)BS * 4 * HW2);   // no fallback flags possible
    }

    if (flags) count_kernel<<<BS, 256, 0, stream>>>(seg, flags);
    hipMemsetAsync(W, 0xFF, Wbytes, stream);      // all cells = -1
    const int total4 = BS * QPB;                  // 2,097,152 threads
    scatter_kernel<<<total4 / 256, 256, 0, stream>>>(grid, seg, flags, W);
    gather_kernel<<<total4 / 256, 256, 0, stream>>>(W, seg, conf, depth, flags, out);
}

// Round 3
// 352.997 us; speedup vs baseline: 1.4724x; 1.4724x over previous
//
#include <hip/hip_runtime.h>

#define HW    256
#define HW2   65536      // HW*HW
#define BS    128
#define NT    1024       // threads per block
#define QPB   16384      // float4 quads per image plane (HW2/4)
#define HQ    8192       // quads per half plane

// Packed-u16 max into LDS via 32-bit CAS. cell in [0,65536), val in [0,65536).
__device__ __forceinline__ void lds_max_u16(unsigned int* W32, int cell, unsigned int val) {
    unsigned int* word = W32 + (cell >> 1);
    unsigned int sh = (cell & 1) << 4;
    unsigned int assumed = *word;
    while (((assumed >> sh) & 0xFFFFu) < val) {
        unsigned int nw = (assumed & ~(0xFFFFu << sh)) | (val << sh);
        unsigned int prev = atomicCAS(word, assumed, nw);
        if (prev == assumed) break;
        assumed = prev;
    }
}

// Two blocks per batch (256 blocks -> all 256 CUs at 1 block/CU with 136KB LDS).
// Both blocks of a pair build the full winner array (phases 0-1 duplicated);
// each block gathers/writes half the outputs (phase 2 split).
// Winner semantics: W[gy,gx] = max l (l = h*256+w), matching the reference
// scatter's last-in-row-major-order-wins; "no writer" (W=0 init) is
// output-equivalent to winner l=0 (both sample (0,0), valid=1). Verified
// against the golden reference in round 1 (absmax 0.0).
__global__ __launch_bounds__(NT, 1) void fused_kernel(
        const float* __restrict__ grid,
        const float* __restrict__ seg,
        const float* __restrict__ conf,
        const float* __restrict__ depth,
        float* __restrict__ out) {
    __shared__ unsigned short Wl[HW2];                     // 128 KB winners
    __shared__ unsigned long long segbits[4][256];         // 8 KB: comp-planar mask bits per quad
    __shared__ int red[16];
    __shared__ int flag_s;

    const int b    = blockIdx.x >> 1;
    const int half = blockIdx.x & 1;
    const int tid  = threadIdx.x;
    const int wave = tid >> 6;
    const int lane = tid & 63;
    unsigned int* W32 = (unsigned int*)Wl;

    const float* segb   = seg   + (size_t)b * HW2;
    const float* confb  = conf  + (size_t)b * HW2;
    const float* depthb = depth + (size_t)b * HW2;

    // ---- Phase 0: zero W; read seg; ballot mask bits; count for fallback --
    {
        uint4* Wz = (uint4*)W32;                  // 8192 uint4
        #pragma unroll
        for (int k = 0; k < 8; ++k) Wz[tid + k * NT] = make_uint4(0u, 0u, 0u, 0u);
    }
    unsigned long long mbits = 0ULL;   // per-thread: bit (k*4+j) = mask of pixel (tid+k*NT)*4+j
    int cnt = 0;
    {
        const float4* s4 = (const float4*)segb;
        #pragma unroll
        for (int k = 0; k < 16; ++k) {
            int i = tid + k * NT;                 // quad index; i>>6 == wave + k*16
            float4 v = s4[i];
            bool px = v.x > 0.5f, py = v.y > 0.5f, pz = v.z > 0.5f, pw = v.w > 0.5f;
            unsigned long long bx = __ballot(px);
            unsigned long long by = __ballot(py);
            unsigned long long bz = __ballot(pz);
            unsigned long long bw = __ballot(pw);
            if (lane == 0) {
                int wi = wave + k * 16;
                segbits[0][wi] = bx; segbits[1][wi] = by;
                segbits[2][wi] = bz; segbits[3][wi] = bw;
                cnt += __popcll(bx) + __popcll(by) + __popcll(bz) + __popcll(bw);
            }
            unsigned long long q = (px ? 1ULL : 0ULL) | (py ? 2ULL : 0ULL) |
                                   (pz ? 4ULL : 0ULL) | (pw ? 8ULL : 0ULL);
            mbits |= q << (k * 4);
        }
    }
    if (lane == 0) red[wave] = cnt;
    __syncthreads();
    if (tid == 0) {
        int t = 0;
        #pragma unroll
        for (int w = 0; w < 16; ++w) t += red[w];
        flag_s = (t == 0) ? 1 : 0;
    }
    __syncthreads();
    const int flagb = flag_s;

    // ---- Phase 1: scatter (LDS CAS-max) over the FULL batch plane --------
    {
        const float4* gx4 = (const float4*)(grid + (size_t)(2 * b) * HW2);
        const float4* gy4 = (const float4*)(grid + (size_t)(2 * b + 1) * HW2);
        int masked_max = -1;  // masked pixels (gridm==0) all target cell (128,128)
        #pragma unroll 4
        for (int k = 0; k < 16; ++k) {
            int i = tid + k * NT;
            float4 X = gx4[i];
            float4 Y = gy4[i];
            int hw0 = i * 4;
            float xa[4] = {X.x, X.y, X.z, X.w};
            float ya[4] = {Y.x, Y.y, Y.z, Y.w};
            #pragma unroll
            for (int j = 0; j < 4; ++j) {
                bool m = flagb || ((mbits >> (k * 4 + j)) & 1ULL);
                if (m) {
                    float fx = (xa[j] + 1.0f) * 0.5f * 256.0f;  // trunc==floor (>=0)
                    float fy = (ya[j] + 1.0f) * 0.5f * 256.0f;
                    int gxi = min(max((int)fx, 0), HW - 1);
                    int gyi = min(max((int)fy, 0), HW - 1);
                    lds_max_u16(W32, gyi * HW + gxi, (unsigned int)(hw0 + j));
                } else {
                    masked_max = hw0 + j;   // k increases -> last seen is max
                }
            }
        }
        int mm = masked_max;
        for (int off = 32; off > 0; off >>= 1) mm = max(mm, __shfl_xor(mm, off));
        if (lane == 0 && mm >= 0)
            lds_max_u16(W32, 128 * HW + 128, (unsigned int)mm);
    }
    __syncthreads();

    // ---- Phase 2: gather + write THIS block's half of the outputs --------
    // l -> ix=(l&255)&~1, iy=(l>>8)&~1  (round-half-even of uv-0.5 picks even)
    float4* out4 = (float4*)out;
    const size_t dkBase = (size_t)(b * 3) * QPB;
    const size_t O1q = (size_t)BS * 3 * QPB + (size_t)b * QPB;
    const size_t O2q = (size_t)BS * 4 * QPB + (size_t)b * QPB;
    #pragma unroll 4
    for (int k = 0; k < 8; ++k) {
        int i = half * HQ + tid + k * NT;
        uint2 wv = *(const uint2*)(Wl + 4 * i);   // 4 packed u16 winners
        unsigned la[4] = {wv.x & 0xFFFFu, wv.x >> 16, wv.y & 0xFFFFu, wv.y >> 16};
        float o0[4], o1[4], o2[4], oc[4], om[4];
        #pragma unroll
        for (int j = 0; j < 4; ++j) {
            unsigned l = la[j];
            int ix = (int)(l & 255u) & ~1;
            int iy = (int)(l >> 8) & ~1;
            int off = iy * HW + ix;
            int q = off >> 2;
            float m;
            if (flagb) m = 1.0f;
            else       m = (float)((segbits[off & 3][q >> 6] >> (q & 63)) & 1ULL);
            o0[j] = ((float)ix / 280.0f) * m;
            o1[j] = ((float)iy / 280.0f) * m;
            o2[j] = depthb[off] * m;
            oc[j] = confb[off];
            om[j] = m;
        }
        out4[dkBase + i]           = make_float4(o0[0], o0[1], o0[2], o0[3]);
        out4[dkBase + QPB + i]     = make_float4(o1[0], o1[1], o1[2], o1[3]);
        out4[dkBase + 2 * QPB + i] = make_float4(o2[0], o2[1], o2[2], o2[3]);
        out4[O1q + i]              = make_float4(oc[0], oc[1], oc[2], oc[3]);
        out4[O2q + i]              = make_float4(om[0], om[1], om[2], om[3]);
    }
}

extern "C" void kernel_launch(void* const* d_in, const int* in_sizes, int n_in,
                              void* d_out, int out_size, void* d_ws, size_t ws_size,
                              hipStream_t stream) {
    const float* grid  = (const float*)d_in[0];
    const float* seg   = (const float*)d_in[1];
    const float* conf  = (const float*)d_in[2];
    const float* depth = (const float*)d_in[3];
    float* out = (float*)d_out;
    fused_kernel<<<BS * 2, NT, 0, stream>>>(grid, seg, conf, depth, out);
}

// Round 4
// 343.584 us; speedup vs baseline: 1.5127x; 1.0274x over previous
//
#include <hip/hip_runtime.h>

#define HW    256
#define HW2   65536      // HW*HW
#define BS    128
#define NT    1024       // threads per block
#define QPB   16384      // float4 quads per image plane (HW2/4)
#define HQ    8192       // quads per half plane

// Block = (batch, y-half). 256 blocks, 1/CU (136 KB LDS), all 256 CUs busy.
// Each block owns winner cells with gy>>7==half as u32 in LDS -> native
// ds_max_u32 (no CAS loop), and each pixel's scatter lands in exactly one
// block (total atomic count 1x, was 2x with duplicated full-plane scatter).
// Pair blocks b and b+128 map to the same XCD under round-robin dispatch, so
// the duplicated grid/seg reads hit L2.
// Winner semantics: W[gy,gx] = max l (l=h*256+w) == reference scatter's
// last-in-row-major-order-wins; "no writer" (init 0) is output-equivalent to
// winner l=0 (both sample (0,0), valid). Verified absmax 0.0 in rounds 1,3.
__global__ __launch_bounds__(NT, 1) void fused_kernel(
        const float* __restrict__ grid,
        const float* __restrict__ seg,
        const float* __restrict__ conf,
        const float* __restrict__ depth,
        float* __restrict__ out) {
    __shared__ unsigned int Wl[HW2 / 2];                   // 128 KB: own-half winners (u32)
    __shared__ unsigned long long segbits[4][256];         // 8 KB: comp-planar mask bits per quad
    __shared__ int red[16];
    __shared__ int flag_s;

    const int b    = blockIdx.x & (BS - 1);
    const int half = blockIdx.x >> 7;
    const int tid  = threadIdx.x;
    const int wave = tid >> 6;
    const int lane = tid & 63;

    const float* segb   = seg   + (size_t)b * HW2;
    const float* confb  = conf  + (size_t)b * HW2;
    const float* depthb = depth + (size_t)b * HW2;

    // ---- Phase 0: zero W; read seg; ballot mask bits; count for fallback --
    {
        uint4* Wz = (uint4*)Wl;                   // 8192 uint4
        #pragma unroll
        for (int k = 0; k < 8; ++k) Wz[tid + k * NT] = make_uint4(0u, 0u, 0u, 0u);
    }
    unsigned long long mbits = 0ULL;   // bit (k*4+j) = mask of pixel (tid+k*NT)*4+j
    int cnt = 0;
    {
        const float4* s4 = (const float4*)segb;
        #pragma unroll
        for (int k = 0; k < 16; ++k) {
            int i = tid + k * NT;                 // quad index; i>>6 == wave + k*16
            float4 v = s4[i];
            bool px = v.x > 0.5f, py = v.y > 0.5f, pz = v.z > 0.5f, pw = v.w > 0.5f;
            unsigned long long bx = __ballot(px);
            unsigned long long by = __ballot(py);
            unsigned long long bz = __ballot(pz);
            unsigned long long bw = __ballot(pw);
            if (lane == 0) {
                int wi = wave + k * 16;
                segbits[0][wi] = bx; segbits[1][wi] = by;
                segbits[2][wi] = bz; segbits[3][wi] = bw;
                cnt += __popcll(bx) + __popcll(by) + __popcll(bz) + __popcll(bw);
            }
            unsigned long long q = (px ? 1ULL : 0ULL) | (py ? 2ULL : 0ULL) |
                                   (pz ? 4ULL : 0ULL) | (pw ? 8ULL : 0ULL);
            mbits |= q << (k * 4);
        }
    }
    if (lane == 0) red[wave] = cnt;
    __syncthreads();
    if (tid == 0) {
        int t = 0;
        #pragma unroll
        for (int w = 0; w < 16; ++w) t += red[w];
        flag_s = (t == 0) ? 1 : 0;
    }
    __syncthreads();
    const int flagb = flag_s;

    // ---- Phase 1: scatter own-half cells via native ds_max_u32 -----------
    {
        const float4* gx4 = (const float4*)(grid + (size_t)(2 * b) * HW2);
        const float4* gy4 = (const float4*)(grid + (size_t)(2 * b + 1) * HW2);
        int masked_max = -1;  // masked pixels (gridm==0) all target cell (128,128)
        #pragma unroll 4
        for (int k = 0; k < 16; ++k) {
            int i = tid + k * NT;
            float4 X = gx4[i];
            float4 Y = gy4[i];
            int hw0 = i * 4;
            float xa[4] = {X.x, X.y, X.z, X.w};
            float ya[4] = {Y.x, Y.y, Y.z, Y.w};
            #pragma unroll
            for (int j = 0; j < 4; ++j) {
                bool m = flagb || ((mbits >> (k * 4 + j)) & 1ULL);
                if (m) {
                    float fx = (xa[j] + 1.0f) * 0.5f * 256.0f;  // trunc==floor (>=0)
                    float fy = (ya[j] + 1.0f) * 0.5f * 256.0f;
                    int gxi = min(max((int)fx, 0), HW - 1);
                    int gyi = min(max((int)fy, 0), HW - 1);
                    if ((gyi >> 7) == half)
                        atomicMax(&Wl[(gyi & 127) * HW + gxi], (unsigned int)(hw0 + j));
                } else {
                    masked_max = hw0 + j;   // k increases -> last seen is max
                }
            }
        }
        int mm = masked_max;
        for (int off = 32; off > 0; off >>= 1) mm = max(mm, __shfl_xor(mm, off));
        if (half == 1 && lane == 0 && mm >= 0)   // cell (128,128) lives in half 1
            atomicMax(&Wl[(128 & 127) * HW + 128], (unsigned int)mm);
    }
    __syncthreads();

    // ---- Phase 2: gather + write this half's rows from own LDS W ---------
    // l -> ix=(l&255)&~1, iy=(l>>8)&~1  (round-half-even of uv-0.5 picks even)
    float4* out4 = (float4*)out;
    const size_t dkBase = (size_t)(b * 3) * QPB;
    const size_t O1q = (size_t)BS * 3 * QPB + (size_t)b * QPB;
    const size_t O2q = (size_t)BS * 4 * QPB + (size_t)b * QPB;
    #pragma unroll 4
    for (int k = 0; k < 8; ++k) {
        int i = tid + k * NT;                      // local quad in this half
        uint4 wv = ((const uint4*)Wl)[i];          // 4 u32 winners
        unsigned la[4] = {wv.x, wv.y, wv.z, wv.w};
        float o0[4], o1[4], o2[4], oc[4], om[4];
        #pragma unroll
        for (int j = 0; j < 4; ++j) {
            unsigned l = la[j];
            int ix = (int)(l & 255u) & ~1;
            int iy = (int)(l >> 8) & ~1;
            int off = iy * HW + ix;
            int q = off >> 2;
            float m;
            if (flagb) m = 1.0f;
            else       m = (float)((segbits[off & 3][q >> 6] >> (q & 63)) & 1ULL);
            o0[j] = ((float)ix / 280.0f) * m;
            o1[j] = ((float)iy / 280.0f) * m;
            o2[j] = depthb[off] * m;
            oc[j] = confb[off];
            om[j] = m;
        }
        size_t gq = (size_t)half * HQ + i;         // global quad in full plane
        out4[dkBase + gq]           = make_float4(o0[0], o0[1], o0[2], o0[3]);
        out4[dkBase + QPB + gq]     = make_float4(o1[0], o1[1], o1[2], o1[3]);
        out4[dkBase + 2 * QPB + gq] = make_float4(o2[0], o2[1], o2[2], o2[3]);
        out4[O1q + gq]              = make_float4(oc[0], oc[1], oc[2], oc[3]);
        out4[O2q + gq]              = make_float4(om[0], om[1], om[2], om[3]);
    }
}

extern "C" void kernel_launch(void* const* d_in, const int* in_sizes, int n_in,
                              void* d_out, int out_size, void* d_ws, size_t ws_size,
                              hipStream_t stream) {
    const float* grid  = (const float*)d_in[0];
    const float* seg   = (const float*)d_in[1];
    const float* conf  = (const float*)d_in[2];
    const float* depth = (const float*)d_in[3];
    float* out = (float*)d_out;
    fused_kernel<<<BS * 2, NT, 0, stream>>>(grid, seg, conf, depth, out);
}

// Round 6
// 319.331 us; speedup vs baseline: 1.6276x; 1.0759x over previous
//
#include <hip/hip_runtime.h>

#define HW    256
#define HW2   65536      // HW*HW
#define BS    128
#define NT    1024       // threads per block
#define QPB   16384      // float4 quads per image plane (HW2/4)
#define QQ    4096       // quads per quarter plane (64 rows)

// Block = (batch, y-quarter). 512 blocks, 2/CU (74 KB LDS each) -> 32 waves/CU
// (full occupancy). Each block owns winner cells with gy>>6==quarter as u32 in
// LDS (native ds_max_u32); every pixel's scatter lands in exactly one block.
// The 4 sibling blocks of a batch (b, b+128, b+256, b+384) map to the same XCD
// under round-robin dispatch and are co-resident, so duplicated grid/seg reads
// L2-hit.
// Winner semantics: W[gy,gx] = max l (l=h*256+w) == reference scatter's
// last-in-row-major-order-wins; "no writer" (init 0) is output-equivalent to
// winner l=0 (both sample (0,0), valid). Verified absmax 0.0 in rounds 1,3,4.
__global__ __launch_bounds__(NT, 8) void fused_kernel(
        const float* __restrict__ grid,
        const float* __restrict__ seg,
        const float* __restrict__ conf,
        const float* __restrict__ depth,
        float* __restrict__ out) {
    __shared__ unsigned int Wl[HW2 / 4];                   // 64 KB: own-quarter winners (u32)
    __shared__ unsigned long long segbits[4][256];         // 8 KB: comp-planar mask bits per quad
    __shared__ int red[16];
    __shared__ int flag_s;

    const int b       = blockIdx.x & (BS - 1);
    const int quarter = blockIdx.x >> 7;                   // 0..3
    const int tid  = threadIdx.x;
    const int wave = tid >> 6;
    const int lane = tid & 63;

    const float* segb   = seg   + (size_t)b * HW2;
    const float* confb  = conf  + (size_t)b * HW2;
    const float* depthb = depth + (size_t)b * HW2;

    // ---- Phase 0: zero W; read seg; ballot mask bits; count for fallback --
    {
        uint4* Wz = (uint4*)Wl;                   // 4096 uint4
        #pragma unroll
        for (int k = 0; k < 4; ++k) Wz[tid + k * NT] = make_uint4(0u, 0u, 0u, 0u);
    }
    unsigned long long mbits = 0ULL;   // bit (k*4+j) = mask of pixel (tid+k*NT)*4+j
    int cnt = 0;
    {
        const float4* s4 = (const float4*)segb;
        #pragma unroll
        for (int k = 0; k < 16; ++k) {
            int i = tid + k * NT;                 // quad index; i>>6 == wave + k*16
            float4 v = s4[i];
            bool px = v.x > 0.5f, py = v.y > 0.5f, pz = v.z > 0.5f, pw = v.w > 0.5f;
            unsigned long long bx = __ballot(px);
            unsigned long long by = __ballot(py);
            unsigned long long bz = __ballot(pz);
            unsigned long long bw = __ballot(pw);
            if (lane == 0) {
                int wi = wave + k * 16;
                segbits[0][wi] = bx; segbits[1][wi] = by;
                segbits[2][wi] = bz; segbits[3][wi] = bw;
                cnt += __popcll(bx) + __popcll(by) + __popcll(bz) + __popcll(bw);
            }
            unsigned long long q = (px ? 1ULL : 0ULL) | (py ? 2ULL : 0ULL) |
                                   (pz ? 4ULL : 0ULL) | (pw ? 8ULL : 0ULL);
            mbits |= q << (k * 4);
        }
    }
    if (lane == 0) red[wave] = cnt;
    __syncthreads();
    if (tid == 0) {
        int t = 0;
        #pragma unroll
        for (int w = 0; w < 16; ++w) t += red[w];
        flag_s = (t == 0) ? 1 : 0;
    }
    __syncthreads();
    const int flagb = flag_s;

    // ---- Phase 1: scatter own-quarter cells via native ds_max_u32 --------
    {
        const float4* gx4 = (const float4*)(grid + (size_t)(2 * b) * HW2);
        const float4* gy4 = (const float4*)(grid + (size_t)(2 * b + 1) * HW2);
        int masked_max = -1;  // masked pixels (gridm==0) all target cell (128,128)
        #pragma unroll 4
        for (int k = 0; k < 16; ++k) {
            int i = tid + k * NT;
            float4 X = gx4[i];
            float4 Y = gy4[i];
            int hw0 = i * 4;
            float xa[4] = {X.x, X.y, X.z, X.w};
            float ya[4] = {Y.x, Y.y, Y.z, Y.w};
            #pragma unroll
            for (int j = 0; j < 4; ++j) {
                bool m = flagb || ((mbits >> (k * 4 + j)) & 1ULL);
                if (m) {
                    float fx = (xa[j] + 1.0f) * 0.5f * 256.0f;  // trunc==floor (>=0)
                    float fy = (ya[j] + 1.0f) * 0.5f * 256.0f;
                    int gxi = min(max((int)fx, 0), HW - 1);
                    int gyi = min(max((int)fy, 0), HW - 1);
                    if ((gyi >> 6) == quarter)
                        atomicMax(&Wl[(gyi & 63) * HW + gxi], (unsigned int)(hw0 + j));
                } else {
                    masked_max = hw0 + j;   // k increases -> last seen is max
                }
            }
        }
        int mm = masked_max;
        for (int off = 32; off > 0; off >>= 1) mm = max(mm, __shfl_xor(mm, off));
        if (quarter == 2 && lane == 0 && mm >= 0)   // cell (128,128): 128>>6 == 2
            atomicMax(&Wl[(128 & 63) * HW + 128], (unsigned int)mm);
    }
    __syncthreads();

    // ---- Phase 2: gather + write this quarter's rows from own LDS W ------
    // l -> ix=(l&255)&~1, iy=(l>>8)&~1  (round-half-even of uv-0.5 picks even)
    float4* out4 = (float4*)out;
    const size_t dkBase = (size_t)(b * 3) * QPB;
    const size_t O1q = (size_t)BS * 3 * QPB + (size_t)b * QPB;
    const size_t O2q = (size_t)BS * 4 * QPB + (size_t)b * QPB;
    #pragma unroll 4
    for (int k = 0; k < 4; ++k) {
        int i = tid + k * NT;                      // local quad in this quarter
        uint4 wv = ((const uint4*)Wl)[i];          // 4 u32 winners
        unsigned la[4] = {wv.x, wv.y, wv.z, wv.w};
        float o0[4], o1[4], o2[4], oc[4], om[4];
        #pragma unroll
        for (int j = 0; j < 4; ++j) {
            unsigned l = la[j];
            int ix = (int)(l & 255u) & ~1;
            int iy = (int)(l >> 8) & ~1;
            int off = iy * HW + ix;
            int q = off >> 2;
            float m;
            if (flagb) m = 1.0f;
            else       m = (float)((segbits[off & 3][q >> 6] >> (q & 63)) & 1ULL);
            o0[j] = ((float)ix / 280.0f) * m;
            o1[j] = ((float)iy / 280.0f) * m;
            o2[j] = depthb[off] * m;
            oc[j] = confb[off];
            om[j] = m;
        }
        size_t gq = (size_t)quarter * QQ + i;      // global quad in full plane
        out4[dkBase + gq]           = make_float4(o0[0], o0[1], o0[2], o0[3]);
        out4[dkBase + QPB + gq]     = make_float4(o1[0], o1[1], o1[2], o1[3]);
        out4[dkBase + 2 * QPB + gq] = make_float4(o2[0], o2[1], o2[2], o2[3]);
        out4[O1q + gq]              = make_float4(oc[0], oc[1], oc[2], oc[3]);
        out4[O2q + gq]              = make_float4(om[0], om[1], om[2], om[3]);
    }
}

extern "C" void kernel_launch(void* const* d_in, const int* in_sizes, int n_in,
                              void* d_out, int out_size, void* d_ws, size_t ws_size,
                              hipStream_t stream) {
    const float* grid  = (const float*)d_in[0];
    const float* seg   = (const float*)d_in[1];
    const float* conf  = (const float*)d_in[2];
    const float* depth = (const float*)d_in[3];
    float* out = (float*)d_out;
    fused_kernel<<<BS * 4, NT, 0, stream>>>(grid, seg, conf, depth, out);
}